// Round 1
// baseline (909.114 us; speedup 1.0000x reference)
//
#include <hip/hip_runtime.h>

// Problem constants (z: [4, 64, 32, 32, 32] f32, embedding: [1024, 64] f32)
#define CH     64
#define KC     1024
#define SP     32768              // 32*32*32
#define NBATCH 4
#define NTOK   (NBATCH * SP)      // 131072
#define CHUNK  128
#define NCHUNK (KC / CHUNK)       // 8

// d_out flat layout (all float32): z_q, loss, perplexity, indices, mean(dist)
#define OFF_ZQ   0
#define OFF_LOSS (NBATCH * CH * SP)      // 8388608
#define OFF_PERP (OFF_LOSS + 1)
#define OFF_IDX  (OFF_PERP + 1)          // 8388610
#define OFF_MEAN (OFF_IDX + NTOK)        // 8519682

// workspace layout (32-bit words)
// [0,1024)      int   hist
// [1024]        float sum_z2
// [1025]        float sum_e2
// [1026,1090)   float sum_zc[64]
// [1090,1154)   float sum_ec[64]
// [1154,2178)   float enorm[1024]
#define WS_WORDS 2178

__global__ void init_ws(int* ws) {
    int i = blockIdx.x * 256 + threadIdx.x;
    if (i < WS_WORDS) ws[i] = 0;
}

// per-channel sums of embedding + total sum of squares (one wave)
__global__ __launch_bounds__(64) void embed_col_stats(const float* __restrict__ e,
                                                      float* __restrict__ sum_ec,
                                                      float* __restrict__ sums) {
    int c = threadIdx.x;  // 0..63
    float s1 = 0.f, s2 = 0.f;
    for (int k = 0; k < KC; ++k) {
        float v = e[k * CH + c];
        s1 += v;
        s2 = fmaf(v, v, s2);
    }
    sum_ec[c] = s1;
    for (int off = 32; off; off >>= 1) s2 += __shfl_down(s2, off);
    if (c == 0) sums[1] = s2;
}

// ||e_k||^2 for each code
__global__ __launch_bounds__(256) void embed_norms(const float* __restrict__ e,
                                                   float* __restrict__ enorm) {
    int k = blockIdx.x * 256 + threadIdx.x;  // grid 4 x 256 = 1024
    const float4* row = (const float4*)(e + (size_t)k * CH);
    float n = 0.f;
#pragma unroll
    for (int j = 0; j < CH / 4; ++j) {
        float4 v = row[j];
        n += v.x * v.x + v.y * v.y + v.z * v.z + v.w * v.w;
    }
    enorm[k] = n;
}

// sum z^2 (scalar) and per-channel sum of z. Each block covers 4096 contiguous
// elements -> single channel per block (4096 divides 32768).
__global__ __launch_bounds__(256) void z_stats(const float* __restrict__ z,
                                               float* __restrict__ sums,
                                               float* __restrict__ sum_zc) {
    const int tid = threadIdx.x;
    const size_t base = (size_t)blockIdx.x * 4096;
    float s1 = 0.f, s2 = 0.f;
#pragma unroll
    for (int j = 0; j < 4; ++j) {
        float4 v = *(const float4*)(z + base + (size_t)tid * 4 + (size_t)j * 1024);
        s1 += v.x + v.y + v.z + v.w;
        s2 += v.x * v.x + v.y * v.y + v.z * v.z + v.w * v.w;
    }
    for (int off = 32; off; off >>= 1) {
        s1 += __shfl_down(s1, off);
        s2 += __shfl_down(s2, off);
    }
    __shared__ float r1[4], r2[4];
    int w = tid >> 6, ln = tid & 63;
    if (ln == 0) { r1[w] = s1; r2[w] = s2; }
    __syncthreads();
    if (tid == 0) {
        float t1 = r1[0] + r1[1] + r1[2] + r1[3];
        float t2 = r2[0] + r2[1] + r2[2] + r2[3];
        int c = (int)((base >> 15) & 63);
        atomicAdd(&sum_zc[c], t1);
        atomicAdd(&sums[0], t2);
    }
}

// main: per-token argmin over codes (LDS-chunked embedding), z_q write,
// indices (as float), LDS histogram -> global hist.
__global__ __launch_bounds__(256) void vq_main(const float* __restrict__ z,
                                               const float* __restrict__ emb,
                                               const float* __restrict__ enorm,
                                               float* __restrict__ out,
                                               int* __restrict__ hist) {
    __shared__ float se[CHUNK * CH];   // 32 KB
    __shared__ float sn[CHUNK];
    __shared__ int   lh[KC];           // 4 KB

    const int tid = threadIdx.x;
    const int t = blockIdx.x * 256 + tid;     // token id, grid = 512
    const int b = t >> 15;
    const int s = t & (SP - 1);

    for (int i = tid; i < KC; i += 256) lh[i] = 0;

    const float* zp = z + (size_t)b * (CH * SP) + s;
    float zr[CH];
#pragma unroll
    for (int c = 0; c < CH; ++c) zr[c] = zp[(size_t)c * SP];

    float best = 3.4e38f;
    int bidx = 0;

    for (int ch = 0; ch < NCHUNK; ++ch) {
        __syncthreads();
        // stage 128 codes x 64 ch into LDS (contiguous, matches global layout)
        const float4* src = (const float4*)(emb + (size_t)ch * CHUNK * CH);
        float4* dst = (float4*)se;
#pragma unroll
        for (int j = 0; j < (CHUNK * CH / 4) / 256; ++j)  // 8 float4 per thread
            dst[tid + j * 256] = src[tid + j * 256];
        if (tid < CHUNK) sn[tid] = enorm[ch * CHUNK + tid];
        __syncthreads();

        for (int kk = 0; kk < CHUNK; ++kk) {
            const float* er = &se[kk * CH];
            float a0 = 0.f, a1 = 0.f, a2 = 0.f, a3 = 0.f;
#pragma unroll
            for (int c = 0; c < CH; c += 4) {
                a0 = fmaf(zr[c + 0], er[c + 0], a0);
                a1 = fmaf(zr[c + 1], er[c + 1], a1);
                a2 = fmaf(zr[c + 2], er[c + 2], a2);
                a3 = fmaf(zr[c + 3], er[c + 3], a3);
            }
            float d = sn[kk] - 2.f * ((a0 + a1) + (a2 + a3));
            if (d < best) { best = d; bidx = ch * CHUNK + kk; }  // strict <: first-min, matches argmin
        }
    }

    // indices output (buffer is float32)
    out[OFF_IDX + t] = (float)bidx;

    // histogram
    atomicAdd(&lh[bidx], 1);
    __syncthreads();
    for (int i = tid; i < KC; i += 256) {
        int v = lh[i];
        if (v) atomicAdd(&hist[i], v);
    }

    // z_q = z + (e[bidx] - z)  (straight-through forward value)
    const float4* eq = (const float4*)(emb + (size_t)bidx * CH);
    float* oq = out + OFF_ZQ + (size_t)b * (CH * SP) + s;
#pragma unroll
    for (int j = 0; j < CH / 4; ++j) {
        float4 v = eq[j];
        int c = 4 * j;
        oq[(size_t)(c + 0) * SP] = zr[c + 0] + (v.x - zr[c + 0]);
        oq[(size_t)(c + 1) * SP] = zr[c + 1] + (v.y - zr[c + 1]);
        oq[(size_t)(c + 2) * SP] = zr[c + 2] + (v.z - zr[c + 2]);
        oq[(size_t)(c + 3) * SP] = zr[c + 3] + (v.w - zr[c + 3]);
    }
}

__global__ __launch_bounds__(1024) void finalize(const int* __restrict__ hist,
                                                 const float* __restrict__ sums,
                                                 const float* __restrict__ sum_zc,
                                                 const float* __restrict__ sum_ec,
                                                 float* __restrict__ out) {
    __shared__ float red[1024];
    int k = threadIdx.x;
    float p = (float)hist[k] * (1.0f / (float)NTOK);
    red[k] = p * logf(p + 1e-10f);
    __syncthreads();
    for (int off = 512; off; off >>= 1) {
        if (k < off) red[k] += red[k + off];
        __syncthreads();
    }
    if (k == 0) {
        out[OFF_PERP] = expf(-red[0]);
        out[OFF_LOSS] = 0.f;
        double dot = 0.0;
        for (int c = 0; c < CH; ++c) dot += (double)sum_zc[c] * (double)sum_ec[c];
        double mean = ((double)KC * (double)sums[0] + (double)NTOK * (double)sums[1] - 2.0 * dot)
                      / ((double)NTOK * (double)KC);
        out[OFF_MEAN] = (float)mean;
    }
}

extern "C" void kernel_launch(void* const* d_in, const int* in_sizes, int n_in,
                              void* d_out, int out_size, void* d_ws, size_t ws_size,
                              hipStream_t stream) {
    const float* z   = (const float*)d_in[0];
    const float* emb = (const float*)d_in[1];
    float* out = (float*)d_out;

    int*   hist   = (int*)d_ws;
    float* sums   = (float*)d_ws + 1024;   // [0]=sum_z2 [1]=sum_e2
    float* sum_zc = (float*)d_ws + 1026;
    float* sum_ec = (float*)d_ws + 1090;
    float* enorm  = (float*)d_ws + 1154;

    init_ws<<<(WS_WORDS + 255) / 256, 256, 0, stream>>>((int*)d_ws);
    embed_col_stats<<<1, 64, 0, stream>>>(emb, sum_ec, sums);
    embed_norms<<<KC / 256, 256, 0, stream>>>(emb, enorm);
    z_stats<<<(NBATCH * CH * SP) / 4096, 256, 0, stream>>>(z, sums, sum_zc);
    vq_main<<<NTOK / 256, 256, 0, stream>>>(z, emb, enorm, out, hist);
    finalize<<<1, 1024, 0, stream>>>(hist, sums, sum_zc, sum_ec, out);
}

// Round 3
// 410.533 us; speedup vs baseline: 2.2145x; 2.2145x over previous
//
#include <hip/hip_runtime.h>

// Problem constants (z: [4, 64, 32, 32, 32] f32, embedding: [1024, 64] f32)
#define CH     64
#define KC     1024
#define SP     32768              // 32*32*32
#define NBATCH 4
#define NTOK   (NBATCH * SP)      // 131072
#define CHUNK  64                 // codes per LDS chunk
#define NCHUNK (KC / CHUNK)       // 16
#define MTOK   64                 // tokens per block
#define SZZ    68                 // zl row stride (floats): 16B-aligned, bank-spread
#define SZE    68                 // el row stride

// d_out flat layout (all float32): z_q, loss, perplexity, indices, mean(dist)
#define OFF_ZQ   0
#define OFF_LOSS (NBATCH * CH * SP)      // 8388608
#define OFF_PERP (OFF_LOSS + 1)
#define OFF_IDX  (OFF_PERP + 1)          // 8388610
#define OFF_MEAN (OFF_IDX + NTOK)        // 8519682

// workspace layout (32-bit words)
#define WS_WORDS 2178

__global__ void init_ws(int* ws) {
    int i = blockIdx.x * 256 + threadIdx.x;
    if (i < WS_WORDS) ws[i] = 0;
}

// per-channel sums of embedding + total sum of squares (one block, 4 k-strips)
__global__ __launch_bounds__(256) void embed_col_stats(const float* __restrict__ e,
                                                       float* __restrict__ sum_ec,
                                                       float* __restrict__ sums) {
    __shared__ float ls1[256];
    __shared__ float r2[4];
    int tid = threadIdx.x;
    int c = tid & 63;
    int strip = tid >> 6;
    float s1 = 0.f, s2 = 0.f;
    for (int k = strip * 256; k < strip * 256 + 256; ++k) {
        float v = e[k * CH + c];
        s1 += v;
        s2 = fmaf(v, v, s2);
    }
    ls1[tid] = s1;
    for (int off = 32; off; off >>= 1) s2 += __shfl_down(s2, off);
    if ((tid & 63) == 0) r2[tid >> 6] = s2;
    __syncthreads();
    if (strip == 0) sum_ec[c] = ls1[c] + ls1[64 + c] + ls1[128 + c] + ls1[192 + c];
    if (tid == 0) sums[1] = r2[0] + r2[1] + r2[2] + r2[3];
}

// ||e_k||^2 for each code
__global__ __launch_bounds__(256) void embed_norms(const float* __restrict__ e,
                                                   float* __restrict__ enorm) {
    int k = blockIdx.x * 256 + threadIdx.x;  // grid 4 x 256 = 1024
    const float4* row = (const float4*)(e + (size_t)k * CH);
    float n = 0.f;
#pragma unroll
    for (int j = 0; j < CH / 4; ++j) {
        float4 v = row[j];
        n += v.x * v.x + v.y * v.y + v.z * v.z + v.w * v.w;
    }
    enorm[k] = n;
}

// sum z^2 (scalar) and per-channel sum of z.
__global__ __launch_bounds__(256) void z_stats(const float* __restrict__ z,
                                               float* __restrict__ sums,
                                               float* __restrict__ sum_zc) {
    const int tid = threadIdx.x;
    const size_t base = (size_t)blockIdx.x * 4096;
    float s1 = 0.f, s2 = 0.f;
#pragma unroll
    for (int j = 0; j < 4; ++j) {
        float4 v = *(const float4*)(z + base + (size_t)tid * 4 + (size_t)j * 1024);
        s1 += v.x + v.y + v.z + v.w;
        s2 += v.x * v.x + v.y * v.y + v.z * v.z + v.w * v.w;
    }
    for (int off = 32; off; off >>= 1) {
        s1 += __shfl_down(s1, off);
        s2 += __shfl_down(s2, off);
    }
    __shared__ float r1[4], r2[4];
    int w = tid >> 6, ln = tid & 63;
    if (ln == 0) { r1[w] = s1; r2[w] = s2; }
    __syncthreads();
    if (tid == 0) {
        float t1 = r1[0] + r1[1] + r1[2] + r1[3];
        float t2 = r2[0] + r2[1] + r2[2] + r2[3];
        int c = (int)((base >> 15) & 63);
        atomicAdd(&sum_zc[c], t1);
        atomicAdd(&sums[0], t2);
    }
}

// main: register-blocked distance GEMM + argmin, round-1-bitwise arithmetic.
// Block = 64 tokens x 1024 codes (16 chunks of 64). 256 threads.
// Thread tile: 4 tokens (tx = tid&15 -> tokens tx+16i) x 4 codes
//              (ty = tid>>4 -> codes u*16+ty, u=0..3) per chunk.
// zl token-major [t][k] (stride 68), el code-major [c][k] (stride 68):
// one b128 = 4 consecutive k = the 4 stride-4 partial lanes. Each acc float4
// component p chains c = p, p+4, ..., p+60 in ascending order via fmaf —
// bitwise identical to the round-1 (passing) per-code dot product.
__global__ __launch_bounds__(256, 3) void vq_main(const float* __restrict__ z,
                                                  const float* __restrict__ emb,
                                                  const float* __restrict__ enorm,
                                                  float* __restrict__ out,
                                                  int* __restrict__ hist) {
    __shared__ float zl[MTOK * SZZ];     // 17408 B, token-major
    __shared__ float el[CHUNK * SZE];    // 17408 B, code-major (reused for reduce)
    __shared__ float sn[CHUNK];          // 256 B

    const int tid = threadIdx.x;
    const int tx = tid & 15;
    const int ty = tid >> 4;            // 0..15
    const int t0 = blockIdx.x * MTOK;   // first token of this block
    const int bb = t0 >> 15;            // batch index (64 | 32768, never straddles)
    const int s0 = t0 & (SP - 1);

    // ---- stage z tile token-major: zl[t][c] = z[bb][c][s0+t] ----
    // coalesced float4 global reads (4 tokens at one c) + 4-way b32 scatter.
    {
        const float* zbase = z + ((size_t)bb * CH) * SP + s0;
#pragma unroll
        for (int j = 0; j < 4; ++j) {
            int idx = tid + j * 256;        // 0..1023
            int c = idx >> 4;               // 0..63
            int tq = idx & 15;              // token quad
            float4 v = *(const float4*)(zbase + (size_t)c * SP + tq * 4);
            zl[(4 * tq + 0) * SZZ + c] = v.x;
            zl[(4 * tq + 1) * SZZ + c] = v.y;
            zl[(4 * tq + 2) * SZZ + c] = v.z;
            zl[(4 * tq + 3) * SZZ + c] = v.w;
        }
    }

    float bestv[4];
    int besti[4];
#pragma unroll
    for (int i = 0; i < 4; ++i) { bestv[i] = 3.4e38f; besti[i] = 0; }

    for (int ch = 0; ch < NCHUNK; ++ch) {
        __syncthreads();   // prev chunk's el reads done (covers zl stage @ch0)
        // ---- stage e chunk code-major, k-contiguous: direct b128 writes ----
        const float4* esrc = (const float4*)(emb + (size_t)ch * CHUNK * CH);
#pragma unroll
        for (int j = 0; j < 4; ++j) {
            int idx = tid + j * 256;        // 0..1023
            int code = idx >> 4;            // 0..63
            int kq = idx & 15;
            *(float4*)&el[code * SZE + kq * 4] = esrc[idx];
        }
        if (tid < CHUNK) sn[tid] = enorm[ch * CHUNK + tid];
        __syncthreads();

        float4 acc[4][4];   // [token i][code u], components = stride-4 partials
#pragma unroll
        for (int i = 0; i < 4; ++i)
#pragma unroll
            for (int u = 0; u < 4; ++u)
                acc[i][u] = make_float4(0.f, 0.f, 0.f, 0.f);

#pragma unroll 4
        for (int jq = 0; jq < 16; ++jq) {
            float4 zk[4];
#pragma unroll
            for (int i = 0; i < 4; ++i)
                zk[i] = *(const float4*)&zl[(tx + 16 * i) * SZZ + 4 * jq];
            float4 ef[4];
#pragma unroll
            for (int u = 0; u < 4; ++u)
                ef[u] = *(const float4*)&el[(u * 16 + ty) * SZE + 4 * jq];
#pragma unroll
            for (int i = 0; i < 4; ++i)
#pragma unroll
                for (int u = 0; u < 4; ++u) {
                    acc[i][u].x = fmaf(zk[i].x, ef[u].x, acc[i][u].x);
                    acc[i][u].y = fmaf(zk[i].y, ef[u].y, acc[i][u].y);
                    acc[i][u].z = fmaf(zk[i].z, ef[u].z, acc[i][u].z);
                    acc[i][u].w = fmaf(zk[i].w, ef[u].w, acc[i][u].w);
                }
        }

        // per-thread codes strictly ascending over (ch,u): strict < == first-min
#pragma unroll
        for (int u = 0; u < 4; ++u) {
            float nrm = sn[u * 16 + ty];
            int code = ch * CHUNK + u * 16 + ty;
#pragma unroll
            for (int i = 0; i < 4; ++i) {
                // EXACT round-1 expression tree: mul-by-2 then subtract,
                // pairwise partial combine (a0+a1)+(a2+a3).
                float d = nrm - 2.f * ((acc[i][u].x + acc[i][u].y) +
                                       (acc[i][u].z + acc[i][u].w));
                if (d < bestv[i]) { bestv[i] = d; besti[i] = code; }
            }
        }
    }

    __syncthreads();  // el reads done -> safe to overlay reduction arrays on el

    // ---- cross-thread argmin reduction over the 16 ty's sharing a token ----
    float* rv = el;                 // [ty][token]  16*64 floats
    int*   ri = (int*)(el + 1024);  // [ty][token]
    int*   fi = (int*)(el + 2048);  // final index per token
#pragma unroll
    for (int i = 0; i < 4; ++i) {
        int t = tx + 16 * i;
        rv[ty * 64 + t] = bestv[i];
        ri[ty * 64 + t] = besti[i];
    }
    __syncthreads();

    if (tid < MTOK) {
        int t = tid;
        float bv = rv[t];
        int bi = ri[t];
#pragma unroll
        for (int y = 1; y < 16; ++y) {
            float v = rv[y * 64 + t];
            int id = ri[y * 64 + t];
            if (v < bv || (v == bv && id < bi)) { bv = v; bi = id; }
        }
        fi[t] = bi;
        out[OFF_IDX + t0 + t] = (float)bi;      // coalesced
        atomicAdd(&hist[bi], 1);
    }
    __syncthreads();

    // ---- z_q epilogue: z + (e[code] - z), coalesced per channel ----
#pragma unroll
    for (int j = 0; j < 16; ++j) {
        int idx = tid + j * 256;   // 0..4095
        int c = idx >> 6;
        int t = idx & 63;
        int code = fi[t];
        float ev = emb[(size_t)code * CH + c];   // L2-hot gather
        float zv = zl[t * SZZ + c];
        out[OFF_ZQ + ((size_t)bb * CH + c) * SP + s0 + t] = zv + (ev - zv);
    }
}

__global__ __launch_bounds__(1024) void finalize(const int* __restrict__ hist,
                                                 const float* __restrict__ sums,
                                                 const float* __restrict__ sum_zc,
                                                 const float* __restrict__ sum_ec,
                                                 float* __restrict__ out) {
    __shared__ float red[1024];
    int k = threadIdx.x;
    float p = (float)hist[k] * (1.0f / (float)NTOK);
    red[k] = p * logf(p + 1e-10f);
    __syncthreads();
    for (int off = 512; off; off >>= 1) {
        if (k < off) red[k] += red[k + off];
        __syncthreads();
    }
    if (k == 0) {
        out[OFF_PERP] = expf(-red[0]);
        out[OFF_LOSS] = 0.f;
        double dot = 0.0;
        for (int c = 0; c < CH; ++c) dot += (double)sum_zc[c] * (double)sum_ec[c];
        double mean = ((double)KC * (double)sums[0] + (double)NTOK * (double)sums[1] - 2.0 * dot)
                      / ((double)NTOK * (double)KC);
        out[OFF_MEAN] = (float)mean;
    }
}

extern "C" void kernel_launch(void* const* d_in, const int* in_sizes, int n_in,
                              void* d_out, int out_size, void* d_ws, size_t ws_size,
                              hipStream_t stream) {
    const float* z   = (const float*)d_in[0];
    const float* emb = (const float*)d_in[1];
    float* out = (float*)d_out;

    int*   hist   = (int*)d_ws;
    float* sums   = (float*)d_ws + 1024;   // [0]=sum_z2 [1]=sum_e2
    float* sum_zc = (float*)d_ws + 1026;
    float* sum_ec = (float*)d_ws + 1090;
    float* enorm  = (float*)d_ws + 1154;

    init_ws<<<(WS_WORDS + 255) / 256, 256, 0, stream>>>((int*)d_ws);
    embed_col_stats<<<1, 256, 0, stream>>>(emb, sum_ec, sums);
    embed_norms<<<KC / 256, 256, 0, stream>>>(emb, enorm);
    z_stats<<<(NBATCH * CH * SP) / 4096, 256, 0, stream>>>(z, sums, sum_zc);
    vq_main<<<NTOK / MTOK, 256, 0, stream>>>(z, emb, enorm, out, hist);
    finalize<<<1, 1024, 0, stream>>>(hist, sums, sum_zc, sum_ec, out);
}